// Round 3
// baseline (226.728 us; speedup 1.0000x reference)
//
#include <hip/hip_runtime.h>
#include <hip/hip_bf16.h>
#include <float.h>

// Problem constants: S=8192 tokens, E=64 experts, C=256 capacity
constexpr int S = 8192;
constexpr int E = 64;
constexpr int C = 256;
constexpr int EC = E * C;                 // 16384 floats per token region
constexpr int A_BLOCKS = 512;             // fused kernel blocks (4 waves each)
constexpr int TOK_PER_WAVE = S / (A_BLOCKS * 4);  // 4

// ---------------------------------------------------------------------------
// Fused kernel: per-row softmax + top-2 extraction, then the wave streams the
// token's ENTIRE 64x256 output region (zeros + 2 hot values) with float4
// stores. One wave per token (4 tokens per wave); no separate memset pass.
// Output region for token s starts at out + 1 + s*16384 (the +1 is the l_aux
// slot), so each region = 3 head scalars + 4095 aligned float4 + 1 tail scalar.
// Also emits per-block l_aux partials (me/ce sums) to ws.
// ---------------------------------------------------------------------------
__global__ __launch_bounds__(256) void fused_kernel(
        const float* __restrict__ logits,
        const float* __restrict__ mask1,
        const float* __restrict__ mask2,
        const float* __restrict__ loc1,
        const float* __restrict__ loc2,
        float* __restrict__ out,
        float* __restrict__ ws_partials) {
    __shared__ float me_s[4][64];
    __shared__ float ce_s[4][64];

    const int lane = threadIdx.x & 63;
    const int wave = threadIdx.x >> 6;
    const int gwave = blockIdx.x * 4 + wave;      // 0..2047

    float me_acc = 0.f;
    float ce_acc = 0.f;

    for (int r = 0; r < TOK_PER_WAVE; ++r) {
        const int s = gwave * TOK_PER_WAVE + r;

        // --- softmax over E=64 (one lane per expert) ---
        const float x = logits[(size_t)s * E + lane];
        float mx = x;
        #pragma unroll
        for (int off = 32; off > 0; off >>= 1) mx = fmaxf(mx, __shfl_xor(mx, off));
        const float ex = __expf(x - mx);
        float sum = ex;
        #pragma unroll
        for (int off = 32; off > 0; off >>= 1) sum += __shfl_xor(sum, off);
        const float g = ex / sum;

        const float m1v = mask1[(size_t)s * E + lane];
        const float m2v = mask2[(size_t)s * E + lane];
        me_acc += g;
        ce_acc += m1v;

        // expert indices via ballot over the one-hot masks (exactly one bit set)
        const int e1 = __ffsll(__ballot(m1v > 0.5f)) - 1;
        const int e2 = __ffsll(__ballot(m2v > 0.5f)) - 1;
        const float g1 = __shfl(g, e1);
        const float g2 = __shfl(g, e2);

        // capacity slots: one-hot rows of length C=256; lane scans 4 via float4
        const float4 l1v = *reinterpret_cast<const float4*>(loc1 + (size_t)s * C + lane * 4);
        const float4 l2v = *reinterpret_cast<const float4*>(loc2 + (size_t)s * C + lane * 4);
        const int bm1 = (l1v.x > 0.5f ? 1 : 0) | (l1v.y > 0.5f ? 2 : 0) |
                        (l1v.z > 0.5f ? 4 : 0) | (l1v.w > 0.5f ? 8 : 0);
        const int bm2 = (l2v.x > 0.5f ? 1 : 0) | (l2v.y > 0.5f ? 2 : 0) |
                        (l2v.z > 0.5f ? 4 : 0) | (l2v.w > 0.5f ? 8 : 0);
        const int L1 = __ffsll(__ballot(bm1 != 0)) - 1;
        const int L2 = __ffsll(__ballot(bm2 != 0)) - 1;
        const int c1 = L1 * 4 + (__ffs(__shfl(bm1, L1)) - 1);
        const int c2 = L2 * 4 + (__ffs(__shfl(bm2, L2)) - 1);

        // normalized top-2 gate weights (all lanes hold them)
        const float denom = fmaxf(g1 + g2, FLT_EPSILON);
        const float w1 = g1 / denom;
        const float w2 = g2 / denom;
        const int h1 = e1 * C + c1;   // flat hot index within [0, 16384)
        const int h2 = e2 * C + c2;

        // --- stream the full 16384-float region: head(3) + 4095*float4 + tail(1) ---
        float* __restrict__ base = out + 1 + (size_t)s * EC;
        if (lane < 3) {
            base[lane] = (lane == h1) ? w1 : ((lane == h2) ? w2 : 0.f);
        } else if (lane == 3) {
            base[EC - 1] = ((EC - 1) == h1) ? w1 : (((EC - 1) == h2) ? w2 : 0.f);
        }
        #pragma unroll 4
        for (int i = lane; i < 4095; i += 64) {
            const int f0 = 3 + 4 * i;   // base+f0 is 16B aligned
            float4 v;
            v.x = (f0     == h1) ? w1 : ((f0     == h2) ? w2 : 0.f);
            v.y = (f0 + 1 == h1) ? w1 : ((f0 + 1 == h2) ? w2 : 0.f);
            v.z = (f0 + 2 == h1) ? w1 : ((f0 + 2 == h2) ? w2 : 0.f);
            v.w = (f0 + 3 == h1) ? w1 : ((f0 + 3 == h2) ? w2 : 0.f);
            *reinterpret_cast<float4*>(base + f0) = v;
        }
    }

    me_s[wave][lane] = me_acc;
    ce_s[wave][lane] = ce_acc;
    __syncthreads();
    if (threadIdx.x < 64) {
        const float me_b = me_s[0][lane] + me_s[1][lane] + me_s[2][lane] + me_s[3][lane];
        const float ce_b = ce_s[0][lane] + ce_s[1][lane] + ce_s[2][lane] + ce_s[3][lane];
        ws_partials[(size_t)blockIdx.x * 128 + lane]      = me_b;
        ws_partials[(size_t)blockIdx.x * 128 + 64 + lane] = ce_b;
    }
}

// ---------------------------------------------------------------------------
// l_aux = (E/S^2) * sum_e me_sum[e]*ce_sum[e], written to out[0].
// ---------------------------------------------------------------------------
__global__ __launch_bounds__(256) void laux_kernel(const float* __restrict__ ws_partials,
                                                   float* __restrict__ out) {
    __shared__ float mes[4][64];
    __shared__ float ces[4][64];
    const int e = threadIdx.x & 63;
    const int q = threadIdx.x >> 6;
    float me = 0.f, ce = 0.f;
    for (int b = q; b < A_BLOCKS; b += 4) {
        me += ws_partials[(size_t)b * 128 + e];
        ce += ws_partials[(size_t)b * 128 + 64 + e];
    }
    mes[q][e] = me;
    ces[q][e] = ce;
    __syncthreads();
    if (threadIdx.x < 64) {
        const float m = mes[0][e] + mes[1][e] + mes[2][e] + mes[3][e];
        const float c = ces[0][e] + ces[1][e] + ces[2][e] + ces[3][e];
        float prod = m * c;
        #pragma unroll
        for (int off = 32; off > 0; off >>= 1) prod += __shfl_xor(prod, off);
        if (e == 0) out[0] = prod * (float)E / ((float)S * (float)S);
    }
}

extern "C" void kernel_launch(void* const* d_in, const int* in_sizes, int n_in,
                              void* d_out, int out_size, void* d_ws, size_t ws_size,
                              hipStream_t stream) {
    const float* logits = (const float*)d_in[0];
    const float* mask1  = (const float*)d_in[1];
    const float* mask2  = (const float*)d_in[2];
    const float* loc1   = (const float*)d_in[3];
    const float* loc2   = (const float*)d_in[4];
    float* out = (float*)d_out;
    float* ws  = (float*)d_ws;

    // single pass: compute + full-region streaming write (no separate memset)
    fused_kernel<<<A_BLOCKS, 256, 0, stream>>>(logits, mask1, mask2, loc1, loc2, out, ws);

    // l_aux reduce
    laux_kernel<<<1, 256, 0, stream>>>(ws, out);
}

// Round 4
// 157.550 us; speedup vs baseline: 1.4391x; 1.4391x over previous
//
#include <hip/hip_runtime.h>
#include <hip/hip_bf16.h>
#include <float.h>

// Problem constants: S=8192 tokens, E=64 experts, C=256 capacity
constexpr int S = 8192;
constexpr int E = 64;
constexpr int C = 256;
constexpr int EC = E * C;          // 16384 floats per token region
constexpr int P_BLOCKS = 256;      // partials kernel blocks (4 waves x 8 tokens = 8192)

// ---------------------------------------------------------------------------
// Kernel 1: one block per token. All 4 waves zero-fill the token's 64 KB
// output region with pure float4 stores (fill-kernel shape). Wave 0 computes
// the row math (softmax + ballots) in parallel. __syncthreads (drains vmcnt
// before s_barrier) orders the fill before the two hot-element overwrites.
// Token region = out + 1 + s*16384 (the +1 is the l_aux slot), so:
// 3 head scalars + 4095 aligned float4 + 1 tail scalar.
// ---------------------------------------------------------------------------
__global__ __launch_bounds__(256) void token_write_kernel(
        const float* __restrict__ logits,
        const float* __restrict__ mask1,
        const float* __restrict__ mask2,
        const float* __restrict__ loc1,
        const float* __restrict__ loc2,
        float* __restrict__ out) {
    const int s    = blockIdx.x;
    const int tid  = threadIdx.x;
    const int lane = tid & 63;
    const int wave = tid >> 6;
    float* __restrict__ base = out + 1 + (size_t)s * EC;

    // Wave 0: issue all input loads up front (latency hides under the fill).
    float x = 0.f, m1v = 0.f, m2v = 0.f;
    float4 l1v = make_float4(0, 0, 0, 0), l2v = make_float4(0, 0, 0, 0);
    if (wave == 0) {
        x    = logits[(size_t)s * E + lane];
        m1v  = mask1[(size_t)s * E + lane];
        m2v  = mask2[(size_t)s * E + lane];
        l1v  = *reinterpret_cast<const float4*>(loc1 + (size_t)s * C + lane * 4);
        l2v  = *reinterpret_cast<const float4*>(loc2 + (size_t)s * C + lane * 4);
    }

    // All waves: zero the region. Head/tail scalars + 4095 float4.
    if (tid < 3)       base[tid]      = 0.f;
    else if (tid == 3) base[EC - 1]   = 0.f;
    const float4 z = make_float4(0.f, 0.f, 0.f, 0.f);
    #pragma unroll
    for (int k = 0; k < 16; ++k) {
        const int j = tid + 256 * k;          // float4 index, stride 1 KB/wave-instr
        if (j < 4095)
            *reinterpret_cast<float4*>(base + 3 + 4 * j) = z;
    }

    // Wave 0: softmax + top-2 extraction (ballot on one-hot inputs).
    float w1 = 0.f, w2 = 0.f;
    int h1 = 0, h2 = 0;
    if (wave == 0) {
        float mx = x;
        #pragma unroll
        for (int off = 32; off > 0; off >>= 1) mx = fmaxf(mx, __shfl_xor(mx, off));
        const float ex = __expf(x - mx);
        float sum = ex;
        #pragma unroll
        for (int off = 32; off > 0; off >>= 1) sum += __shfl_xor(sum, off);
        const float g = ex / sum;

        const int e1 = __ffsll(__ballot(m1v > 0.5f)) - 1;
        const int e2 = __ffsll(__ballot(m2v > 0.5f)) - 1;
        const float g1 = __shfl(g, e1);
        const float g2 = __shfl(g, e2);

        const int bm1 = (l1v.x > 0.5f ? 1 : 0) | (l1v.y > 0.5f ? 2 : 0) |
                        (l1v.z > 0.5f ? 4 : 0) | (l1v.w > 0.5f ? 8 : 0);
        const int bm2 = (l2v.x > 0.5f ? 1 : 0) | (l2v.y > 0.5f ? 2 : 0) |
                        (l2v.z > 0.5f ? 4 : 0) | (l2v.w > 0.5f ? 8 : 0);
        const int L1 = __ffsll(__ballot(bm1 != 0)) - 1;
        const int L2 = __ffsll(__ballot(bm2 != 0)) - 1;
        const int c1 = L1 * 4 + (__ffs(__shfl(bm1, L1)) - 1);
        const int c2 = L2 * 4 + (__ffs(__shfl(bm2, L2)) - 1);

        const float denom = fmaxf(g1 + g2, FLT_EPSILON);
        w1 = g1 / denom;
        w2 = g2 / denom;
        h1 = e1 * C + c1;
        h2 = e2 * C + c2;
    }

    __syncthreads();   // all zero-stores drained (vmcnt(0) before s_barrier)

    if (tid == 0) base[h1] = w1;   // tid 0/1 are in wave 0: registers valid
    if (tid == 1) base[h2] = w2;
}

// ---------------------------------------------------------------------------
// Kernel 2: l_aux partials. Reads only logits + mask1 (4 MB total).
// 256 blocks x 4 waves x 8 tokens. Per-block me/ce sums -> ws (deterministic).
// ---------------------------------------------------------------------------
__global__ __launch_bounds__(256) void partials_kernel(
        const float* __restrict__ logits,
        const float* __restrict__ mask1,
        float* __restrict__ ws_partials) {
    __shared__ float me_s[4][64];
    __shared__ float ce_s[4][64];
    const int lane  = threadIdx.x & 63;
    const int wave  = threadIdx.x >> 6;
    const int gwave = blockIdx.x * 4 + wave;   // 0..1023

    float me_acc = 0.f, ce_acc = 0.f;
    #pragma unroll
    for (int r = 0; r < 8; ++r) {
        const int s = gwave * 8 + r;
        const float x = logits[(size_t)s * E + lane];
        float mx = x;
        #pragma unroll
        for (int off = 32; off > 0; off >>= 1) mx = fmaxf(mx, __shfl_xor(mx, off));
        const float ex = __expf(x - mx);
        float sum = ex;
        #pragma unroll
        for (int off = 32; off > 0; off >>= 1) sum += __shfl_xor(sum, off);
        me_acc += ex / sum;
        ce_acc += mask1[(size_t)s * E + lane];
    }

    me_s[wave][lane] = me_acc;
    ce_s[wave][lane] = ce_acc;
    __syncthreads();
    if (threadIdx.x < 64) {
        const float me_b = me_s[0][lane] + me_s[1][lane] + me_s[2][lane] + me_s[3][lane];
        const float ce_b = ce_s[0][lane] + ce_s[1][lane] + ce_s[2][lane] + ce_s[3][lane];
        ws_partials[(size_t)blockIdx.x * 128 + lane]      = me_b;
        ws_partials[(size_t)blockIdx.x * 128 + 64 + lane] = ce_b;
    }
}

// ---------------------------------------------------------------------------
// Kernel 3: l_aux = (E/S^2) * sum_e me_sum[e]*ce_sum[e] -> out[0].
// ---------------------------------------------------------------------------
__global__ __launch_bounds__(256) void laux_kernel(const float* __restrict__ ws_partials,
                                                   float* __restrict__ out) {
    __shared__ float mes[4][64];
    __shared__ float ces[4][64];
    const int e = threadIdx.x & 63;
    const int q = threadIdx.x >> 6;
    float me = 0.f, ce = 0.f;
    for (int b = q; b < P_BLOCKS; b += 4) {
        me += ws_partials[(size_t)b * 128 + e];
        ce += ws_partials[(size_t)b * 128 + 64 + e];
    }
    mes[q][e] = me;
    ces[q][e] = ce;
    __syncthreads();
    if (threadIdx.x < 64) {
        const float m = mes[0][e] + mes[1][e] + mes[2][e] + mes[3][e];
        const float c = ces[0][e] + ces[1][e] + ces[2][e] + ces[3][e];
        float prod = m * c;
        #pragma unroll
        for (int off = 32; off > 0; off >>= 1) prod += __shfl_xor(prod, off);
        if (e == 0) out[0] = prod * (float)E / ((float)S * (float)S);
    }
}

extern "C" void kernel_launch(void* const* d_in, const int* in_sizes, int n_in,
                              void* d_out, int out_size, void* d_ws, size_t ws_size,
                              hipStream_t stream) {
    const float* logits = (const float*)d_in[0];
    const float* mask1  = (const float*)d_in[1];
    const float* mask2  = (const float*)d_in[2];
    const float* loc1   = (const float*)d_in[3];
    const float* loc2   = (const float*)d_in[4];
    float* out = (float*)d_out;
    float* ws  = (float*)d_ws;

    // single pass over the 537 MB output: pure-fill + 2 hot overwrites per token
    token_write_kernel<<<S, 256, 0, stream>>>(logits, mask1, mask2, loc1, loc2, out);

    // l_aux pipeline (reads only logits + mask1)
    partials_kernel<<<P_BLOCKS, 256, 0, stream>>>(logits, mask1, ws);
    laux_kernel<<<1, 256, 0, stream>>>(ws, out);
}